// Round 2
// baseline (5534.290 us; speedup 1.0000x reference)
//
#include <hip/hip_runtime.h>
#include <hip/hip_bf16.h>
#include <cstddef>
#include <cstdint>

typedef __hip_bfloat16 bf16;

// ---------- helpers ----------
__device__ inline float ldf(const float* p) { return *p; }
__device__ inline float ldf(const bf16* p) { return __bfloat162float(*p); }
__device__ inline void stf(float* p, float v) { *p = v; }
__device__ inline void stf(bf16* p, float v) { *p = __float2bfloat16(v); }

// Problem constants
// BS=32, T=64, NE=32, NA=8, ED=128, H=512, A=512, NH=8, HD=64, NACT=32

// ---------- generic tiled GEMM ----------
// C[M,N] = act(A[M,K] @ B + bias), f32 accumulate.
// BT: B is [N,K] row-major (C = A @ B^T); else B is [K,N] row-major.
// QG: A-row gather for q projection: ar = (m>>3)*32 + (m&7)
// ACT: 0 = none, 1 = relu
// MASKQ: zero output row where scenario mask (row = ((b*64+t)*8+a))
template<int ACT, bool BT, bool QG, bool MASKQ, typename TA, typename TB, typename TC>
__global__ __launch_bounds__(256) void gemm_k(
    const TA* __restrict__ A, const TB* __restrict__ B,
    const float* __restrict__ bias, TC* __restrict__ C,
    int M, int N, int K, const int* __restrict__ smask)
{
    const int BM = 64, BN = 64, BK = 16;
    __shared__ float As[BM][BK + 1];
    __shared__ float Bs[BK][BN + 1];
    int tid = threadIdx.x;
    int n0 = blockIdx.x * BN;
    int m0 = blockIdx.y * BM;
    int ty = tid >> 4, tx = tid & 15;
    float acc[4][4] = {};

    for (int k0 = 0; k0 < K; k0 += BK) {
        // A tile: 64x16 = 1024 elems, 4 per thread
        #pragma unroll
        for (int i = 0; i < 4; ++i) {
            int l = tid * 4 + i;
            int r = l >> 4, c = l & 15;
            int gm = m0 + r;
            int ar = QG ? (((gm >> 3) << 5) | (gm & 7)) : gm;
            As[r][c] = ldf(&A[(size_t)ar * K + k0 + c]);
        }
        // B tile
        #pragma unroll
        for (int i = 0; i < 4; ++i) {
            int l = tid * 4 + i;
            if (BT) {
                int n = l >> 4, kk = l & 15;
                int gn = n0 + n;
                Bs[kk][n] = (gn < N) ? ldf(&B[(size_t)gn * K + k0 + kk]) : 0.f;
            } else {
                int r = l >> 6, c = l & 63;
                int gn = n0 + c;
                Bs[r][c] = (gn < N) ? ldf(&B[(size_t)(k0 + r) * N + gn]) : 0.f;
            }
        }
        __syncthreads();
        #pragma unroll
        for (int kk = 0; kk < BK; ++kk) {
            float a[4], b[4];
            #pragma unroll
            for (int i = 0; i < 4; ++i) a[i] = As[ty + i * 16][kk];
            #pragma unroll
            for (int j = 0; j < 4; ++j) b[j] = Bs[kk][tx + j * 16];
            #pragma unroll
            for (int i = 0; i < 4; ++i)
                #pragma unroll
                for (int j = 0; j < 4; ++j) acc[i][j] += a[i] * b[j];
        }
        __syncthreads();
    }

    #pragma unroll
    for (int i = 0; i < 4; ++i) {
        int gm = m0 + ty + i * 16;
        bool mz = false;
        if (MASKQ) {
            int a_ = gm & 7, t_ = (gm >> 3) & 63, b_ = gm >> 9;
            mz = smask[((b_ << 6) + t_) * 32 + a_] != 0;
        }
        #pragma unroll
        for (int j = 0; j < 4; ++j) {
            int gn = n0 + tx + j * 16;
            if (gn < N) {
                float v = acc[i][j] + bias[gn];
                if (ACT == 1) v = fmaxf(v, 0.f);
                if (MASKQ && mz) v = 0.f;
                stf(&C[(size_t)gm * N + gn], v);
            }
        }
    }
}

// ---------- attention: one wave per (b,t,h) ----------
// q: [BS*T*8, 512] bf16, k/v: [BS*T*32, 512] bf16
// writes xs [T, BS*8, 512] f32 (att masked by scenario mask)
__global__ __launch_bounds__(64) void attn_k(
    const bf16* __restrict__ qb, const bf16* __restrict__ kb, const bf16* __restrict__ vb,
    const int* __restrict__ obs, const int* __restrict__ smask, float* __restrict__ xs)
{
    __shared__ float qs[8 * 64], ks[32 * 64], vs[32 * 64], wsm[8 * 32];
    int bid = blockIdx.x;
    int h = bid & 7;
    int bt = bid >> 3;          // b*64 + t
    int t = bt & 63, b = bt >> 6;
    int tid = threadIdx.x;

    #pragma unroll
    for (int i = 0; i < 8; ++i) {
        int l = tid + i * 64;   // 0..511
        int e = l >> 6, d = l & 63;
        qs[l] = __bfloat162float(qb[((size_t)bt * 8 + e) * 512 + h * 64 + d]);
    }
    #pragma unroll
    for (int i = 0; i < 32; ++i) {
        int l = tid + i * 64;   // 0..2047
        int e = l >> 6, d = l & 63;
        ks[l] = __bfloat162float(kb[((size_t)bt * 32 + e) * 512 + h * 64 + d]);
        vs[l] = __bfloat162float(vb[((size_t)bt * 32 + e) * 512 + h * 64 + d]);
    }
    __syncthreads();

    int ql = tid >> 3, jl = tid & 7;
    float s[4];
    #pragma unroll
    for (int c = 0; c < 4; ++c) {
        int kl = jl + c * 8;
        float acc = 0.f;
        for (int d = 0; d < 64; ++d) acc += qs[ql * 64 + d] * ks[kl * 64 + d];
        acc *= 0.125f;   // 1/sqrt(64)
        bool m = obs[(((size_t)bt * 32) + ql) * 32 + kl] != 0;
        s[c] = m ? -__builtin_inff() : acc;
    }
    float mx = fmaxf(fmaxf(s[0], s[1]), fmaxf(s[2], s[3]));
    for (int off = 1; off < 8; off <<= 1) mx = fmaxf(mx, __shfl_xor(mx, off));
    float e4[4]; float sum = 0.f;
    bool allmasked = (mx == -__builtin_inff());
    #pragma unroll
    for (int c = 0; c < 4; ++c) {
        e4[c] = (allmasked || s[c] == -__builtin_inff()) ? 0.f : expf(s[c] - mx);
        sum += e4[c];
    }
    for (int off = 1; off < 8; off <<= 1) sum += __shfl_xor(sum, off);
    float inv = (sum > 0.f) ? 1.f / sum : 0.f;
    #pragma unroll
    for (int c = 0; c < 4; ++c) wsm[ql * 32 + jl + c * 8] = e4[c] * inv;
    __syncthreads();

    bool amask = smask[(size_t)bt * 32 + ql] != 0;
    #pragma unroll
    for (int dd = 0; dd < 8; ++dd) {
        int d = jl + dd * 8;
        float acc = 0.f;
        for (int kl = 0; kl < 32; ++kl) acc += wsm[ql * 32 + kl] * vs[kl * 64 + d];
        if (amask) acc = 0.f;
        xs[((size_t)(t * 256 + b * 8 + ql)) * 512 + h * 64 + d] = acc;
    }
}

// ---------- GRU gate fusion ----------
// gi_t: [256,1536] f32 (includes bih); gh: [256,1536] f32 (includes bhh)
__global__ __launch_bounds__(256) void gru_gate_k(
    const float* __restrict__ gi_t, const float* __restrict__ gh,
    const float* __restrict__ hprev, float* __restrict__ hnext,
    const int* __restrict__ smask, float* __restrict__ hs_out, int t)
{
    int idx = blockIdx.x * 256 + threadIdx.x;  // 0..131071
    int row = idx >> 9, j = idx & 511;
    size_t gbase = (size_t)row * 1536 + j;
    float ir = gi_t[gbase], iz = gi_t[gbase + 512], in_ = gi_t[gbase + 1024];
    float hr = gh[gbase],   hz = gh[gbase + 512],   hn = gh[gbase + 1024];
    float r = 1.f / (1.f + expf(-(ir + hr)));
    float z = 1.f / (1.f + expf(-(iz + hz)));
    float n = tanhf(in_ + r * hn);
    float hp = hprev[(size_t)row * 512 + j];
    float hN = (1.f - z) * n + z * hp;
    hnext[(size_t)row * 512 + j] = hN;
    int b = row >> 3, a = row & 7;
    bool m = smask[((b << 6) + t) * 32 + a] != 0;
    hs_out[((size_t)((b << 6) + t) * 8 + a) * 512 + j] = m ? 0.f : hN;
}

// ---------- launch ----------
extern "C" void kernel_launch(void* const* d_in, const int* in_sizes, int n_in,
                              void* d_out, int out_size, void* d_ws, size_t ws_size,
                              hipStream_t stream)
{
    const float* inputs = (const float*)d_in[0];
    const int*   obs    = (const int*)d_in[1];
    const int*   smask  = (const int*)d_in[2];
    const float* h0     = (const float*)d_in[3];
    const float* W1  = (const float*)d_in[4];  const float* b1  = (const float*)d_in[5];
    const float* Wq  = (const float*)d_in[6];  const float* bq  = (const float*)d_in[7];
    const float* Wk  = (const float*)d_in[8];  const float* bk  = (const float*)d_in[9];
    const float* Wv  = (const float*)d_in[10]; const float* bv  = (const float*)d_in[11];
    const float* Wih = (const float*)d_in[12]; const float* bih = (const float*)d_in[13];
    const float* Whh = (const float*)d_in[14]; const float* bhh = (const float*)d_in[15];
    const float* Wo  = (const float*)d_in[16]; const float* bo  = (const float*)d_in[17];

    char* ws = (char*)d_ws;
    // region A [0, 64MB): x bf16 [65536,512]; later xs f32 [16384,512] (32MB)
    bf16*  x  = (bf16*)(ws + 0);
    float* xs = (float*)(ws + 0);
    // region B [64MB, 208MB): q,k,v bf16; later gi f32 [16384,1536] (96MB)
    bf16* qb = (bf16*)(ws + 67108864ull);
    bf16* kb = (bf16*)(ws + 83886080ull);
    bf16* vb = (bf16*)(ws + 150994944ull);
    float* gi = (float*)(ws + 67108864ull);
    // region C [208MB, ~211MB)
    float* gh    = (float*)(ws + 218103808ull);
    float* hbuf0 = (float*)(ws + 219676672ull);
    float* hbuf1 = (float*)(ws + 220200960ull);

    float* out    = (float*)d_out;
    float* hs_out = out + 524288;   // qout is [16384,32] = 524288 elems

    // 1. fc1: x = relu(inputs @ W1 + b1)   [65536,128]x[128,512]
    gemm_k<1, false, false, false><<<dim3(8, 1024), 256, 0, stream>>>(
        inputs, W1, b1, x, 65536, 512, 128, nullptr);
    // 2. q (NA rows only, gathered): [16384,512]
    gemm_k<0, false, true, false><<<dim3(8, 256), 256, 0, stream>>>(
        x, Wq, bq, qb, 16384, 512, 512, nullptr);
    // 3. k: [65536,512]
    gemm_k<0, false, false, false><<<dim3(8, 1024), 256, 0, stream>>>(
        x, Wk, bk, kb, 65536, 512, 512, nullptr);
    // 4. v = relu(...): [65536,512]
    gemm_k<1, false, false, false><<<dim3(8, 1024), 256, 0, stream>>>(
        x, Wv, bv, vb, 65536, 512, 512, nullptr);
    // 5. attention -> xs [T,256,512] f32 (overwrites x region; x is dead)
    attn_k<<<dim3(16384), 64, 0, stream>>>(qb, kb, vb, obs, smask, xs);
    // 6. gi = xs @ Wih^T + bih : [16384,1536] f32 (overwrites q/k/v region; dead)
    gemm_k<0, true, false, false><<<dim3(24, 256), 256, 0, stream>>>(
        xs, Wih, bih, gi, 16384, 1536, 512, nullptr);
    // 7. GRU over T=64 steps
    const float* hprev = h0;
    for (int t = 0; t < 64; ++t) {
        float* hnext = (t & 1) ? hbuf1 : hbuf0;
        gemm_k<0, true, false, false><<<dim3(24, 4), 256, 0, stream>>>(
            hprev, Whh, bhh, gh, 256, 1536, 512, nullptr);
        gru_gate_k<<<dim3(512), 256, 0, stream>>>(
            gi + (size_t)t * 256 * 1536, gh, hprev, hnext, smask, hs_out, t);
        hprev = hnext;
    }
    // 8. qout = hs @ Wo + bo (masked rows of hs are 0; re-mask qout to kill bias)
    gemm_k<0, false, false, true><<<dim3(1, 256), 256, 0, stream>>>(
        hs_out, Wo, bo, out, 16384, 32, 512, smask);
}